// Round 10
// baseline (193.248 us; speedup 1.0000x reference)
//
#include <hip/hip_runtime.h>
#include <hip/hip_bf16.h>
#include <stdint.h>

// ---------------------------------------------------------------------------
// SelfAttention2d: B=4, C=256, H=W=64 (N=4096), NUM_HEADS=4 (hd=64), GROUPS=8
// R21: consolidation. (1) gn_partial stats reverted to R12's 512-block scalar
//      form (R19's 128-block f32x4 version halved stats-phase parallelism and
//      cost ~1-2us); weight-cvt stays vectorized (192+64 blocks). (2) gn_apply
//      keeps R20's f32x4 body, stat-gather back to 16-lane. (3) qkv/proj
//      GEMMs: 2-phase staged compute — rows 0..63 are each wave's oldest 8
//      DMAs, so vmcnt(8)+barrier -> compute tt0..3 overlapped with rows
//      64..127 landing -> vmcnt(0)+barrier -> tt4..7. Hides half the staging
//      drain (the vmcnt(0)-before-barrier stall). flash frozen at R17 plateau
//      (91.7us; issue-bound: MFMA 35% + VALU 53% of SIMD issue).
// ---------------------------------------------------------------------------

#define B_  4
#define C_  256
#define N_  4096
#define NH_ 4
#define HD_ 64
#define G_  8
#define CPG_ 32
#define GRP_ELEMS (CPG_ * N_)

typedef __attribute__((ext_vector_type(8))) short short8;
typedef __attribute__((ext_vector_type(4))) float f32x4;
typedef __attribute__((ext_vector_type(4))) unsigned short us4;

__device__ __forceinline__ unsigned short f2bf(float f) {
  union { float f; unsigned u; } v; v.f = f;
  unsigned r = v.u + 0x7FFFu + ((v.u >> 16) & 1u);
  return (unsigned short)(r >> 16);
}

// packed fp32x2 -> bf16x2 (v_cvt_pk_bf16_f32 on gfx950)
__device__ __forceinline__ unsigned pkbf2(float a, float b) {
  __hip_bfloat162 h = __float22bfloat162_rn(make_float2(a, b));
  unsigned r; __builtin_memcpy(&r, &h, sizeof(r)); return r;
}

// async 16B/lane global->LDS DMA; LDS dest = uniform base + lane*16
__device__ __forceinline__ void dma16(const unsigned short* g, unsigned short* l) {
  __builtin_amdgcn_global_load_lds(
      (const __attribute__((address_space(1))) unsigned int*)(g),
      (__attribute__((address_space(3))) unsigned int*)(l), 16, 0, 0);
}

// ---------------------------------------------------------------------------
// Kernel 1: gn_partial (blocks 0..511, scalar — full-chip parallelism) +
// weight conversion (blocks 512..703 wq, 704..767 wp; 4 elem/thread).
// ---------------------------------------------------------------------------
__global__ void gn_partial_cvt(const float* __restrict__ x, float* __restrict__ partial,
                               const float* __restrict__ qkvw, const float* __restrict__ projw,
                               unsigned short* __restrict__ wq, unsigned short* __restrict__ wp) {
  __shared__ float ls[8];
  int t = threadIdx.x;
  if (blockIdx.x >= 512) {
    if (blockIdx.x < 704) {
      int i = (blockIdx.x - 512) * 1024 + t * 4;      // 192*1024 = 768*256
      f32x4 v = *reinterpret_cast<const f32x4*>(qkvw + i);
      us4 o; o[0] = f2bf(v[0]); o[1] = f2bf(v[1]); o[2] = f2bf(v[2]); o[3] = f2bf(v[3]);
      *reinterpret_cast<us4*>(wq + i) = o;
    } else {
      int i = (blockIdx.x - 704) * 1024 + t * 4;      // 64*1024 = 256*256
      f32x4 v = *reinterpret_cast<const f32x4*>(projw + i);
      us4 o; o[0] = f2bf(v[0]); o[1] = f2bf(v[1]); o[2] = f2bf(v[2]); o[3] = f2bf(v[3]);
      *reinterpret_cast<us4*>(wp + i) = o;
    }
    return;
  }
  int idx = blockIdx.x;
  int slice = idx & 15, g = (idx >> 4) & 7, b = idx >> 7;
  const float* base = x + (size_t)(b * C_ + g * CPG_) * N_ + slice * 256;
  float s = 0.f, sq = 0.f;
#pragma unroll
  for (int cc = 0; cc < CPG_; cc++) {
    float v = base[(size_t)cc * N_ + t];
    s += v; sq += v * v;
  }
#pragma unroll
  for (int off = 32; off; off >>= 1) {
    s  += __shfl_down(s,  off, 64);
    sq += __shfl_down(sq, off, 64);
  }
  int wave = t >> 6, lane = t & 63;
  if (lane == 0) { ls[wave * 2] = s; ls[wave * 2 + 1] = sq; }
  __syncthreads();
  if (t == 0) {
    float S = ls[0] + ls[2] + ls[4] + ls[6];
    float SQ = ls[1] + ls[3] + ls[5] + ls[7];
    partial[idx * 2] = S; partial[idx * 2 + 1] = SQ;
  }
}

// ---------------------------------------------------------------------------
// Kernel 2: normalize + transpose with INLINE stats. x -> hT (B,N,C) bf16.
// f32x4 x-loads (16B/lane), us4 tile stores; 16-lane stat gather (512-entry
// partial); packed b128 hT store epilogue.
// ---------------------------------------------------------------------------
__global__ void gn_apply(const float* __restrict__ x,
                         const float* __restrict__ nw, const float* __restrict__ nb,
                         const float* __restrict__ partial, unsigned short* __restrict__ hT) {
  int nt = blockIdx.x, ct = blockIdx.y, b = blockIdx.z;
  __shared__ __align__(16) unsigned short tile[32][72];
  int t = threadIdx.x;
  int lane = t & 63;
  int grp = b * G_ + ct;
  float s = 0.f, sq = 0.f;
  if (lane < 16) {
    s  = partial[(grp * 16 + lane) * 2];
    sq = partial[(grp * 16 + lane) * 2 + 1];
  }
#pragma unroll
  for (int off = 8; off; off >>= 1) {
    s  += __shfl_down(s,  off, 64);
    sq += __shfl_down(sq, off, 64);
  }
  s  = __shfl(s,  0, 64);
  sq = __shfl(sq, 0, 64);
  const float inv = 1.0f / (float)GRP_ELEMS;
  float mean = s * inv;
  float rstd = rsqrtf(sq * inv - mean * mean + 1e-5f);

  int c_loc = t >> 4;            // 0..15
  int n0 = (t & 15) * 4;         // 0,4,...,60
  const float* xb = x + (size_t)(b * C_ + ct * CPG_) * N_ + nt * 64;
#pragma unroll
  for (int rr = 0; rr < 2; rr++) {
    int cc = rr * 16 + c_loc;
    int c = ct * CPG_ + cc;
    f32x4 v = *reinterpret_cast<const f32x4*>(xb + (size_t)cc * N_ + n0);
    float sc = nw[c] * rstd;
    float ofs = nb[c] - mean * sc;
    us4 o;
    o[0] = f2bf(v[0] * sc + ofs);
    o[1] = f2bf(v[1] * sc + ofs);
    o[2] = f2bf(v[2] * sc + ofs);
    o[3] = f2bf(v[3] * sc + ofs);
    *reinterpret_cast<us4*>(&tile[cc][n0]) = o;
  }
  __syncthreads();
  // packed write: thread handles n = t>>2, 8 consecutive c = (t&3)*8
  int n = t >> 2, c8 = (t & 3) * 8;
  us4 lo, hi;
#pragma unroll
  for (int j = 0; j < 4; j++) lo[j] = tile[c8 + j][n];
#pragma unroll
  for (int j = 0; j < 4; j++) hi[j] = tile[c8 + 4 + j][n];
  unsigned short* outp = hT + ((size_t)(b * N_ + nt * 64 + n)) * C_ + ct * CPG_ + c8;
  *reinterpret_cast<us4*>(outp) = lo;
  *reinterpret_cast<us4*>(outp + 4) = hi;
}

// ---------------------------------------------------------------------------
// Kernel 3: qkv GEMM, 128-n x 128-o blocks. grid 768 (1D XCD-affine).
// R21: 2-phase staged compute — vmcnt(8) covers rows 0..63 (each wave's
// oldest 8 DMAs); compute tt0..3 overlaps rows 64..127 landing.
// ---------------------------------------------------------------------------
__global__ __launch_bounds__(256) void qkv_gemm(
    const unsigned short* __restrict__ hT, const unsigned short* __restrict__ wq,
    const float* __restrict__ qb,
    unsigned short* __restrict__ Qt, unsigned short* __restrict__ Kt,
    unsigned short* __restrict__ V) {
  int ot = blockIdx.x >> 7;
  int nt = (blockIdx.x & 127) >> 2;
  int b  = blockIdx.x & 3;
  int t = threadIdx.x;
  int wave = t >> 6, lane = t & 63, l15 = lane & 15, quad = lane >> 4, l7 = l15 & 7;

  __shared__ __align__(16) unsigned short sh[128 * C_];
  {
    int row0 = wave * 2 + (lane >> 5);
    int col8 = lane & 31;
    int src8 = (col8 & 24) | ((col8 & 7) ^ (row0 & 7));
    const unsigned short* gsrc = hT + ((size_t)(b * N_ + nt * 128 + row0)) * C_ + src8 * 8;
#pragma unroll
    for (int it = 0; it < 16; it++)
      dma16(gsrc + (size_t)it * 8 * C_, sh + (it * 8 + wave * 2) * C_);
  }

  f32x4 acc[2][8];
#pragma unroll
  for (int r = 0; r < 2; r++)
#pragma unroll
    for (int tt = 0; tt < 8; tt++) acc[r][tt] = (f32x4){0.f, 0.f, 0.f, 0.f};

  const short8* arow[2];
#pragma unroll
  for (int r = 0; r < 2; r++)
    arow[r] = reinterpret_cast<const short8*>(
        wq + (size_t)(ot * 128 + wave * 32 + r * 16 + l15) * C_);

  // phase A: rows 0..63 (its 0..7 across all waves = oldest 8 per wave)
  asm volatile("s_waitcnt vmcnt(8)" ::: "memory");
  __syncthreads();
#pragma unroll
  for (int kk = 0; kk < 8; kk++) {
    int g = kk * 4 + quad;
    int col8 = (g & 24) | ((g & 7) ^ l7);
    short8 bfr[4];
#pragma unroll
    for (int tt = 0; tt < 4; tt++)
      bfr[tt] = *reinterpret_cast<const short8*>(&sh[(tt * 16 + l15) * C_ + col8 * 8]);
#pragma unroll
    for (int r = 0; r < 2; r++) {
      short8 a = arow[r][g];
#pragma unroll
      for (int tt = 0; tt < 4; tt++)
        acc[r][tt] = __builtin_amdgcn_mfma_f32_16x16x32_bf16(a, bfr[tt], acc[r][tt], 0, 0, 0);
    }
  }
  // phase B: rows 64..127
  asm volatile("s_waitcnt vmcnt(0)" ::: "memory");
  __syncthreads();
#pragma unroll
  for (int kk = 0; kk < 8; kk++) {
    int g = kk * 4 + quad;
    int col8 = (g & 24) | ((g & 7) ^ l7);
    short8 bfr[4];
#pragma unroll
    for (int tt = 0; tt < 4; tt++)
      bfr[tt] = *reinterpret_cast<const short8*>(&sh[((tt + 4) * 16 + l15) * C_ + col8 * 8]);
#pragma unroll
    for (int r = 0; r < 2; r++) {
      short8 a = arow[r][g];
#pragma unroll
      for (int tt = 0; tt < 4; tt++)
        acc[r][tt + 4] = __builtin_amdgcn_mfma_f32_16x16x32_bf16(a, bfr[tt], acc[r][tt + 4], 0, 0, 0);
    }
  }

  int sec = ot >> 1;                       // 0=Q, 1=K, 2=V
  int head = (ot & 1) * 2 + (wave >> 1);   // head index within batch
  int bh = b * NH_ + head;
  const float SC = 0.125f * 1.44269504088896340736f;  // 1/sqrt(hd) * log2(e)

#pragma unroll
  for (int r = 0; r < 2; r++) {
    int o_glob = ot * 128 + wave * 32 + r * 16;        // row base (bias index)
    int cw = (o_glob & 63) + quad * 4;                 // channel within head
    if (sec == 0) {
#pragma unroll
      for (int tt = 0; tt < 8; tt++) {
        int n = nt * 128 + tt * 16 + l15;
        us4 pk;
#pragma unroll
        for (int i = 0; i < 4; i++)
          pk[i] = f2bf((acc[r][tt][i] + qb[o_glob + quad * 4 + i]) * SC);
        *reinterpret_cast<us4*>(Qt + ((size_t)bh * N_ + n) * HD_ + cw) = pk;
      }
    } else if (sec == 1) {
#pragma unroll
      for (int tt = 0; tt < 8; tt++) {
        int n = nt * 128 + tt * 16 + l15;
        us4 pk;
#pragma unroll
        for (int i = 0; i < 4; i++)
          pk[i] = f2bf(acc[r][tt][i] + qb[o_glob + quad * 4 + i]);
        *reinterpret_cast<us4*>(Kt + ((size_t)bh * N_ + n) * HD_ + cw) = pk;
      }
    } else {
#pragma unroll
      for (int tt = 0; tt < 8; tt++) {
        int n = nt * 128 + tt * 16 + l15;
#pragma unroll
        for (int i = 0; i < 4; i++)
          V[((size_t)bh * HD_ + cw + i) * N_ + n] =
              f2bf(acc[r][tt][i] + qb[o_glob + quad * 4 + i]);
      }
    }
  }
}

// ---------------------------------------------------------------------------
// Kernel 4: flash attention (R17 form, verbatim): R12 structure + setprio.
// 4 waves = 2 qsub x 2 khalf; K+V LDS dbuf per khalf; in-register P
// quad-transpose; la MFMAs for denominator; cross-wave merge epilogue.
// ---------------------------------------------------------------------------
__global__ __launch_bounds__(256, 2) void flash_attn(
    const unsigned short* __restrict__ Qt, const unsigned short* __restrict__ Kt,
    const unsigned short* __restrict__ Vv, unsigned short* __restrict__ aoT) {
  int bh = blockIdx.x & 15, qt = blockIdx.x >> 4;
  int b = bh >> 2, head = bh & 3;
  int t = threadIdx.x;
  int wave = t >> 6, lane = t & 63, l15 = lane & 15, quad = lane >> 4;
  int l7 = l15 & 7;
  int qsub = wave >> 1, khalf = wave & 1;

  const unsigned short* Qb = Qt + (size_t)bh * N_ * HD_;
  const unsigned short* Kb = Kt + (size_t)bh * N_ * HD_;
  const unsigned short* Vb = Vv + (size_t)bh * HD_ * N_;
  int q_base = qt * 128 + qsub * 64;

  __shared__ __align__(16) unsigned char smem[65536];
  unsigned short* Ks = (unsigned short*)smem;
  unsigned short* Vs = (unsigned short*)(smem + 32768);
  float* Obuf = (float*)smem;                 // epilogue reuse: qsub*4352 + c*68 + q
  float* lbuf = (float*)(smem + 34816);       // qsub*64 + q

  const short8 vones = {(short)0x3F80, (short)0x3F80, (short)0x3F80, (short)0x3F80,
                        (short)0x3F80, (short)0x3F80, (short)0x3F80, (short)0x3F80};
  const f32x4 fzero = (f32x4){0.f, 0.f, 0.f, 0.f};

  short8 qf[4][2];
#pragma unroll
  for (int r = 0; r < 4; r++)
#pragma unroll
    for (int h = 0; h < 2; h++)
      qf[r][h] = *reinterpret_cast<const short8*>(
          Qb + (size_t)(q_base + r * 16 + l15) * HD_ + h * 32 + quad * 8);

  f32x4 oa[4][4], la[4];
#pragma unroll
  for (int r = 0; r < 4; r++) {
    la[r] = (f32x4){0.f, 0.f, 0.f, 0.f};
#pragma unroll
    for (int ct = 0; ct < 4; ct++) oa[r][ct] = (f32x4){0.f, 0.f, 0.f, 0.f};
  }

  int i8 = lane >> 3, e = lane & 7;
  int perm = (e ^ i8) * 8;   // XOR swizzle of 8-element groups
  int kvoff = (khalf * 2) * 4096;
  auto stage = [&](int kt2, int buf) {
    int m0 = khalf * 2048 + kt2 * 64;
    unsigned short* Kd = Ks + kvoff + buf * 4096;
    unsigned short* Vd = Vs + kvoff + buf * 4096;
#pragma unroll
    for (int cc = 0; cc < 4; cc++) {
      int c = qsub * 4 + cc;
      dma16(Kb + (size_t)(m0 + c * 8 + i8) * HD_ + perm, Kd + c * 512);
      dma16(Vb + (size_t)(c * 8 + i8) * N_ + m0 + perm, Vd + c * 512);
    }
  };

  stage(0, 0);

#pragma unroll 1
  for (int kt = 0; kt < 32; kt++) {
    int buf = kt & 1;
    if (kt + 1 < 32) {
      stage(kt + 1, buf ^ 1);                          // issue prefetch first
      asm volatile("s_waitcnt vmcnt(8)" ::: "memory"); // wait only tile kt's 8
    } else {
      asm volatile("s_waitcnt vmcnt(0)" ::: "memory");
    }
    __builtin_amdgcn_s_barrier();
    __builtin_amdgcn_s_setprio(1);   // compute phase: favor this wave

    const unsigned short* Kbuf = Ks + kvoff + buf * 4096;
    const unsigned short* Vbuf = Vs + kvoff + buf * 4096;

    short8 kf[4][2], vf[4][2];
#pragma unroll
    for (int tt = 0; tt < 4; tt++)
#pragma unroll
      for (int kh2 = 0; kh2 < 2; kh2++) {
        kf[tt][kh2] = *reinterpret_cast<const short8*>(
            &Kbuf[(tt * 16 + l15) * 64 + (((kh2 * 4 + quad) ^ l7) * 8)]);
        vf[tt][kh2] = *reinterpret_cast<const short8*>(
            &Vbuf[(tt * 16 + l15) * 64 + (((kh2 * 4 + quad) ^ l7) * 8)]);
      }

#pragma unroll
    for (int r = 0; r < 4; r++) {
      f32x4 s[4];
#pragma unroll
      for (int tt = 0; tt < 4; tt++) {
        f32x4 z = __builtin_amdgcn_mfma_f32_16x16x32_bf16(kf[tt][0], qf[r][0], fzero, 0, 0, 0);
        s[tt] = __builtin_amdgcn_mfma_f32_16x16x32_bf16(kf[tt][1], qf[r][1], z, 0, 0, 0);
      }
      // exp2 + pack: lane holds P[key=tt*16+quad*4+i][q=l15] as bf16x2 words.
      unsigned Apk[4], Bpk[4];
#pragma unroll
      for (int tt = 0; tt < 4; tt++) {
        Apk[tt] = pkbf2(__builtin_amdgcn_exp2f(s[tt][0]), __builtin_amdgcn_exp2f(s[tt][1]));
        Bpk[tt] = pkbf2(__builtin_amdgcn_exp2f(s[tt][2]), __builtin_amdgcn_exp2f(s[tt][3]));
      }
      // 4x4 quad transpose (fixed l15): PV B-frag lane (l15,quad) needs
      // P[key=quad*8+j][q=l15] -> permlane32_swap (quad^2) + permlane16_swap
      // (quad^1).
      union { unsigned u[4]; short8 v; } f0, f1;
      {
        auto ua = __builtin_amdgcn_permlane32_swap(Apk[0], Apk[1], false, false);
        auto pa = __builtin_amdgcn_permlane16_swap(ua[0], ua[1], false, false);
        auto ub = __builtin_amdgcn_permlane32_swap(Bpk[0], Bpk[1], false, false);
        auto pb = __builtin_amdgcn_permlane16_swap(ub[0], ub[1], false, false);
        f0.u[0] = pa[0]; f0.u[1] = pb[0]; f0.u[2] = pa[1]; f0.u[3] = pb[1];
        auto uc = __builtin_amdgcn_permlane32_swap(Apk[2], Apk[3], false, false);
        auto pc = __builtin_amdgcn_permlane16_swap(uc[0], uc[1], false, false);
        auto ud = __builtin_amdgcn_permlane32_swap(Bpk[2], Bpk[3], false, false);
        auto pd = __builtin_amdgcn_permlane16_swap(ud[0], ud[1], false, false);
        f1.u[0] = pc[0]; f1.u[1] = pd[0]; f1.u[2] = pc[1]; f1.u[3] = pd[1];
      }
      short8 pf0 = f0.v, pf1 = f1.v;
#pragma unroll
      for (int ct = 0; ct < 4; ct++) {
        oa[r][ct] = __builtin_amdgcn_mfma_f32_16x16x32_bf16(vf[ct][0], pf0, oa[r][ct], 0, 0, 0);
        oa[r][ct] = __builtin_amdgcn_mfma_f32_16x16x32_bf16(vf[ct][1], pf1, oa[r][ct], 0, 0, 0);
      }
      la[r] = __builtin_amdgcn_mfma_f32_16x16x32_bf16(vones, pf0, la[r], 0, 0, 0);
      la[r] = __builtin_amdgcn_mfma_f32_16x16x32_bf16(vones, pf1, la[r], 0, 0, 0);
    }
    __builtin_amdgcn_s_setprio(0);   // staging phase next
  }

  // ---- merge the two key-halves (exact: plain add, no max-sub) ----
  __builtin_amdgcn_s_barrier();
  if (khalf == 1) {
#pragma unroll
    for (int r = 0; r < 4; r++) {
#pragma unroll
      for (int ct = 0; ct < 4; ct++)
#pragma unroll
        for (int i = 0; i < 4; i++)
          Obuf[qsub * 4352 + (ct * 16 + quad * 4 + i) * 68 + r * 16 + l15] = oa[r][ct][i];
      if (quad == 0) lbuf[qsub * 64 + r * 16 + l15] = la[r][0];
    }
  }
  __builtin_amdgcn_s_barrier();
  if (khalf == 0) {
#pragma unroll
    for (int r = 0; r < 4; r++) {
      float inv = 1.0f / (la[r][0] + lbuf[qsub * 64 + r * 16 + l15]);
      int n = q_base + r * 16 + l15;
#pragma unroll
      for (int ct = 0; ct < 4; ct++) {
        const float* ob = &Obuf[qsub * 4352 + (ct * 16 + quad * 4) * 68 + r * 16 + l15];
        union { unsigned u2[2]; us4 v; } w;
        w.u2[0] = pkbf2((oa[r][ct][0] + ob[0]) * inv, (oa[r][ct][1] + ob[68]) * inv);
        w.u2[1] = pkbf2((oa[r][ct][2] + ob[136]) * inv, (oa[r][ct][3] + ob[204]) * inv);
        *reinterpret_cast<us4*>(
            aoT + ((size_t)(b * N_ + n)) * C_ + head * HD_ + ct * 16 + quad * 4) = w.v;
      }
    }
  }
}

// ---------------------------------------------------------------------------
// Kernel 5: proj GEMM + bias + residual, 128-n tiles, 1D XCD-aware grid
// (512 blocks). R21: same 2-phase staged compute as qkv.
// ---------------------------------------------------------------------------
__global__ __launch_bounds__(256) void proj_gemm(
    const unsigned short* __restrict__ aoT, const unsigned short* __restrict__ wp,
    const float* __restrict__ pb, const float* __restrict__ x,
    float* __restrict__ out) {
  int ot = blockIdx.x >> 7;
  int nt = (blockIdx.x & 127) >> 2;
  int b  = blockIdx.x & 3;
  int t = threadIdx.x;
  int wave = t >> 6, lane = t & 63, l15 = lane & 15, quad = lane >> 4, l7 = l15 & 7;
  int o_base = ot * 64 + wave * 16;

  __shared__ __align__(16) unsigned short sh[128 * C_];
  {
    int row0 = wave * 2 + (lane >> 5);
    int col8 = lane & 31;
    int src8 = (col8 & 24) | ((col8 & 7) ^ (row0 & 7));
    const unsigned short* gsrc = aoT + ((size_t)(b * N_ + nt * 128 + row0)) * C_ + src8 * 8;
#pragma unroll
    for (int it = 0; it < 16; it++)
      dma16(gsrc + (size_t)it * 8 * C_, sh + (it * 8 + wave * 2) * C_);
  }

  f32x4 acc[8];
#pragma unroll
  for (int tt = 0; tt < 8; tt++) acc[tt] = (f32x4){0.f, 0.f, 0.f, 0.f};

  const short8* arow = reinterpret_cast<const short8*>(wp + (size_t)(o_base + l15) * C_);

  // phase A: rows 0..63
  asm volatile("s_waitcnt vmcnt(8)" ::: "memory");
  __syncthreads();
#pragma unroll
  for (int kk = 0; kk < 8; kk++) {
    short8 a = arow[kk * 4 + quad];
    int g = kk * 4 + quad;
    int col8 = (g & 24) | ((g & 7) ^ l7);
#pragma unroll
    for (int tt = 0; tt < 4; tt++) {
      short8 bf = *reinterpret_cast<const short8*>(&sh[(tt * 16 + l15) * C_ + col8 * 8]);
      acc[tt] = __builtin_amdgcn_mfma_f32_16x16x32_bf16(a, bf, acc[tt], 0, 0, 0);
    }
  }
  // phase B: rows 64..127
  asm volatile("s_waitcnt vmcnt(0)" ::: "memory");
  __syncthreads();
#pragma unroll
  for (int kk = 0; kk < 8; kk++) {
    short8 a = arow[kk * 4 + quad];
    int g = kk * 4 + quad;
    int col8 = (g & 24) | ((g & 7) ^ l7);
#pragma unroll
    for (int tt = 0; tt < 4; tt++) {
      short8 bf = *reinterpret_cast<const short8*>(&sh[((tt + 4) * 16 + l15) * C_ + col8 * 8]);
      acc[tt + 4] = __builtin_amdgcn_mfma_f32_16x16x32_bf16(a, bf, acc[tt + 4], 0, 0, 0);
    }
  }

#pragma unroll
  for (int tt = 0; tt < 8; tt++) {
    int n = nt * 128 + tt * 16 + l15;
#pragma unroll
    for (int i = 0; i < 4; i++) {
      int o = o_base + quad * 4 + i;
      size_t idx = ((size_t)(b * C_ + o)) * N_ + n;
      out[idx] = acc[tt][i] + pb[o] + x[idx];
    }
  }
}

// ---------------------------------------------------------------------------
extern "C" void kernel_launch(void* const* d_in, const int* in_sizes, int n_in,
                              void* d_out, int out_size, void* d_ws, size_t ws_size,
                              hipStream_t stream) {
  const float* x      = (const float*)d_in[0];
  const float* norm_w = (const float*)d_in[1];
  const float* norm_b = (const float*)d_in[2];
  const float* qkv_w  = (const float*)d_in[3];
  const float* qkv_b  = (const float*)d_in[4];
  const float* proj_w = (const float*)d_in[5];
  const float* proj_b = (const float*)d_in[6];
  float* out = (float*)d_out;

  char* ws = (char*)d_ws;
  size_t off = 0;
  auto alloc = [&](size_t bytes) { size_t o = off; off = (off + bytes + 255) & ~(size_t)255; return o; };
  size_t off_partial = alloc(512 * 2 * sizeof(float));
  size_t off_stats   = alloc(32 * 2 * sizeof(float));   // unused (layout stability)
  size_t off_wq      = alloc((size_t)768 * 256 * 2);
  size_t off_wp      = alloc((size_t)256 * 256 * 2);
  size_t off_hT      = alloc((size_t)B_ * N_ * C_ * 2);
  size_t off_Qt      = alloc((size_t)B_ * NH_ * N_ * HD_ * 2);
  size_t off_Kt      = alloc((size_t)B_ * NH_ * N_ * HD_ * 2);
  size_t off_V       = alloc((size_t)B_ * NH_ * HD_ * N_ * 2);
  size_t off_aoT     = alloc((size_t)B_ * N_ * C_ * 2);
  (void)off_stats;

  float* partial = (float*)(ws + off_partial);
  unsigned short* wq  = (unsigned short*)(ws + off_wq);
  unsigned short* wp  = (unsigned short*)(ws + off_wp);
  unsigned short* hT  = (unsigned short*)(ws + off_hT);
  unsigned short* Qt  = (unsigned short*)(ws + off_Qt);
  unsigned short* Kt  = (unsigned short*)(ws + off_Kt);
  unsigned short* V   = (unsigned short*)(ws + off_V);
  unsigned short* aoT = (unsigned short*)(ws + off_aoT);

  gn_partial_cvt<<<768, 256, 0, stream>>>(x, partial, qkv_w, proj_w, wq, wp);
  gn_apply<<<dim3(64, 8, 4), 256, 0, stream>>>(x, norm_w, norm_b, partial, hT);
  qkv_gemm<<<768, 256, 0, stream>>>(hT, wq, qkv_b, Qt, Kt, V);
  flash_attn<<<512, 256, 0, stream>>>(Qt, Kt, V, aoT);
  proj_gemm<<<512, 256, 0, stream>>>(aoT, wp, proj_b, x, out);
}

// Round 11
// 184.947 us; speedup vs baseline: 1.0449x; 1.0449x over previous
//
#include <hip/hip_runtime.h>
#include <hip/hip_bf16.h>
#include <stdint.h>

// ---------------------------------------------------------------------------
// SelfAttention2d: B=4, C=256, H=W=64 (N=4096), NUM_HEADS=4 (hd=64), GROUPS=8
// R22: revert to the best-measured configuration (R17, 184.4 us total):
//      flash_attn = R12 structure + setprio (issue-bound plateau: MFMA 35% +
//      VALU 54% of SIMD issue; probes R13-R18 all null/regressed);
//      qkv/proj = single-phase staged GEMMs (R21's 2-phase vmcnt split
//      regressed ~8 us: compiler-hoisted weight loads corrupt the vmcnt
//      count, forcing a near-full drain plus a second barrier);
//      gn kernels = original R11 forms (vectorized variants were noise).
// ---------------------------------------------------------------------------

#define B_  4
#define C_  256
#define N_  4096
#define NH_ 4
#define HD_ 64
#define G_  8
#define CPG_ 32
#define GRP_ELEMS (CPG_ * N_)

typedef __attribute__((ext_vector_type(8))) short short8;
typedef __attribute__((ext_vector_type(4))) float f32x4;
typedef __attribute__((ext_vector_type(4))) unsigned short us4;

__device__ __forceinline__ unsigned short f2bf(float f) {
  union { float f; unsigned u; } v; v.f = f;
  unsigned r = v.u + 0x7FFFu + ((v.u >> 16) & 1u);
  return (unsigned short)(r >> 16);
}

// packed fp32x2 -> bf16x2 (v_cvt_pk_bf16_f32 on gfx950)
__device__ __forceinline__ unsigned pkbf2(float a, float b) {
  __hip_bfloat162 h = __float22bfloat162_rn(make_float2(a, b));
  unsigned r; __builtin_memcpy(&r, &h, sizeof(r)); return r;
}

// async 16B/lane global->LDS DMA; LDS dest = uniform base + lane*16
__device__ __forceinline__ void dma16(const unsigned short* g, unsigned short* l) {
  __builtin_amdgcn_global_load_lds(
      (const __attribute__((address_space(1))) unsigned int*)(g),
      (__attribute__((address_space(3))) unsigned int*)(l), 16, 0, 0);
}

// ---------------------------------------------------------------------------
// Kernel 1: gn_partial (blocks 0..511) + weight conversion (blocks 512..1279).
// ---------------------------------------------------------------------------
__global__ void gn_partial_cvt(const float* __restrict__ x, float* __restrict__ partial,
                               const float* __restrict__ qkvw, const float* __restrict__ projw,
                               unsigned short* __restrict__ wq, unsigned short* __restrict__ wp) {
  __shared__ float ls[8];
  int t = threadIdx.x;
  if (blockIdx.x >= 512) {
    int i = (blockIdx.x - 512) * 256 + t;
    if (i < 768 * 256) wq[i] = f2bf(qkvw[i]);
    if (i < 256 * 256) wp[i] = f2bf(projw[i]);
    return;
  }
  int idx = blockIdx.x;
  int slice = idx & 15, g = (idx >> 4) & 7, b = idx >> 7;
  const float* base = x + (size_t)(b * C_ + g * CPG_) * N_ + slice * 256;
  float s = 0.f, sq = 0.f;
#pragma unroll
  for (int cc = 0; cc < CPG_; cc++) {
    float v = base[(size_t)cc * N_ + t];
    s += v; sq += v * v;
  }
#pragma unroll
  for (int off = 32; off; off >>= 1) {
    s  += __shfl_down(s,  off, 64);
    sq += __shfl_down(sq, off, 64);
  }
  int wave = t >> 6, lane = t & 63;
  if (lane == 0) { ls[wave * 2] = s; ls[wave * 2 + 1] = sq; }
  __syncthreads();
  if (t == 0) {
    float S = ls[0] + ls[2] + ls[4] + ls[6];
    float SQ = ls[1] + ls[3] + ls[5] + ls[7];
    partial[idx * 2] = S; partial[idx * 2 + 1] = SQ;
  }
}

// ---------------------------------------------------------------------------
// Kernel 2: normalize + transpose with INLINE stats. x -> hT (B,N,C) bf16.
// ---------------------------------------------------------------------------
__global__ void gn_apply(const float* __restrict__ x,
                         const float* __restrict__ nw, const float* __restrict__ nb,
                         const float* __restrict__ partial, unsigned short* __restrict__ hT) {
  int nt = blockIdx.x, ct = blockIdx.y, b = blockIdx.z;
  __shared__ unsigned short tile[32][72];
  int t = threadIdx.x;
  int lane = t & 63;
  int grp = b * G_ + ct;
  float s = 0.f, sq = 0.f;
  if (lane < 16) {
    s  = partial[(grp * 16 + lane) * 2];
    sq = partial[(grp * 16 + lane) * 2 + 1];
  }
#pragma unroll
  for (int off = 8; off; off >>= 1) {
    s  += __shfl_down(s,  off, 64);
    sq += __shfl_down(sq, off, 64);
  }
  s  = __shfl(s,  0, 64);
  sq = __shfl(sq, 0, 64);
  const float inv = 1.0f / (float)GRP_ELEMS;
  float mean = s * inv;
  float rstd = rsqrtf(sq * inv - mean * mean + 1e-5f);

  int n_loc = t & 63, c_loc = t >> 6;
  const float* xb = x + (size_t)(b * C_ + ct * CPG_) * N_ + nt * 64;
#pragma unroll
  for (int rr = 0; rr < 8; rr++) {
    int cc = rr * 4 + c_loc;
    int c = ct * CPG_ + cc;
    float v = xb[(size_t)cc * N_ + n_loc];
    v = (v - mean) * rstd * nw[c] + nb[c];
    tile[cc][n_loc] = f2bf(v);
  }
  __syncthreads();
  // packed write: thread handles n = t>>2, 8 consecutive c = (t&3)*8
  int n = t >> 2, c8 = (t & 3) * 8;
  us4 lo, hi;
#pragma unroll
  for (int j = 0; j < 4; j++) lo[j] = tile[c8 + j][n];
#pragma unroll
  for (int j = 0; j < 4; j++) hi[j] = tile[c8 + 4 + j][n];
  unsigned short* outp = hT + ((size_t)(b * N_ + nt * 64 + n)) * C_ + ct * CPG_ + c8;
  *reinterpret_cast<us4*>(outp) = lo;
  *reinterpret_cast<us4*>(outp + 4) = hi;
}

// ---------------------------------------------------------------------------
// Kernel 3: qkv GEMM, 128-n x 128-o blocks. grid 768 (1D XCD-affine).
// ---------------------------------------------------------------------------
__global__ __launch_bounds__(256) void qkv_gemm(
    const unsigned short* __restrict__ hT, const unsigned short* __restrict__ wq,
    const float* __restrict__ qb,
    unsigned short* __restrict__ Qt, unsigned short* __restrict__ Kt,
    unsigned short* __restrict__ V) {
  int ot = blockIdx.x >> 7;
  int nt = (blockIdx.x & 127) >> 2;
  int b  = blockIdx.x & 3;
  int t = threadIdx.x;
  int wave = t >> 6, lane = t & 63, l15 = lane & 15, quad = lane >> 4, l7 = l15 & 7;

  __shared__ __align__(16) unsigned short sh[128 * C_];
  {
    int row0 = wave * 2 + (lane >> 5);
    int col8 = lane & 31;
    int src8 = (col8 & 24) | ((col8 & 7) ^ (row0 & 7));
    const unsigned short* gsrc = hT + ((size_t)(b * N_ + nt * 128 + row0)) * C_ + src8 * 8;
#pragma unroll
    for (int it = 0; it < 16; it++)
      dma16(gsrc + (size_t)it * 8 * C_, sh + (it * 8 + wave * 2) * C_);
  }

  f32x4 acc[2][8];
#pragma unroll
  for (int r = 0; r < 2; r++)
#pragma unroll
    for (int tt = 0; tt < 8; tt++) acc[r][tt] = (f32x4){0.f, 0.f, 0.f, 0.f};

  const short8* arow[2];
#pragma unroll
  for (int r = 0; r < 2; r++)
    arow[r] = reinterpret_cast<const short8*>(
        wq + (size_t)(ot * 128 + wave * 32 + r * 16 + l15) * C_);

  asm volatile("s_waitcnt vmcnt(0)" ::: "memory");
  __syncthreads();

#pragma unroll
  for (int kk = 0; kk < 8; kk++) {
    int g = kk * 4 + quad;
    int col8 = (g & 24) | ((g & 7) ^ l7);
    short8 bfr[8];
#pragma unroll
    for (int tt = 0; tt < 8; tt++)
      bfr[tt] = *reinterpret_cast<const short8*>(&sh[(tt * 16 + l15) * C_ + col8 * 8]);
#pragma unroll
    for (int r = 0; r < 2; r++) {
      short8 a = arow[r][g];
#pragma unroll
      for (int tt = 0; tt < 8; tt++)
        acc[r][tt] = __builtin_amdgcn_mfma_f32_16x16x32_bf16(a, bfr[tt], acc[r][tt], 0, 0, 0);
    }
  }

  int sec = ot >> 1;                       // 0=Q, 1=K, 2=V
  int head = (ot & 1) * 2 + (wave >> 1);   // head index within batch
  int bh = b * NH_ + head;
  const float SC = 0.125f * 1.44269504088896340736f;  // 1/sqrt(hd) * log2(e)

#pragma unroll
  for (int r = 0; r < 2; r++) {
    int o_glob = ot * 128 + wave * 32 + r * 16;        // row base (bias index)
    int cw = (o_glob & 63) + quad * 4;                 // channel within head
    if (sec == 0) {
#pragma unroll
      for (int tt = 0; tt < 8; tt++) {
        int n = nt * 128 + tt * 16 + l15;
        us4 pk;
#pragma unroll
        for (int i = 0; i < 4; i++)
          pk[i] = f2bf((acc[r][tt][i] + qb[o_glob + quad * 4 + i]) * SC);
        *reinterpret_cast<us4*>(Qt + ((size_t)bh * N_ + n) * HD_ + cw) = pk;
      }
    } else if (sec == 1) {
#pragma unroll
      for (int tt = 0; tt < 8; tt++) {
        int n = nt * 128 + tt * 16 + l15;
        us4 pk;
#pragma unroll
        for (int i = 0; i < 4; i++)
          pk[i] = f2bf(acc[r][tt][i] + qb[o_glob + quad * 4 + i]);
        *reinterpret_cast<us4*>(Kt + ((size_t)bh * N_ + n) * HD_ + cw) = pk;
      }
    } else {
#pragma unroll
      for (int tt = 0; tt < 8; tt++) {
        int n = nt * 128 + tt * 16 + l15;
#pragma unroll
        for (int i = 0; i < 4; i++)
          V[((size_t)bh * HD_ + cw + i) * N_ + n] =
              f2bf(acc[r][tt][i] + qb[o_glob + quad * 4 + i]);
      }
    }
  }
}

// ---------------------------------------------------------------------------
// Kernel 4: flash attention (R12 structure + T5 setprio phase hinting).
// 4 waves = 2 qsub x 2 khalf; K+V LDS dbuf per khalf; in-register P
// quad-transpose; cross-wave merge epilogue.
// ---------------------------------------------------------------------------
__global__ __launch_bounds__(256, 2) void flash_attn(
    const unsigned short* __restrict__ Qt, const unsigned short* __restrict__ Kt,
    const unsigned short* __restrict__ Vv, unsigned short* __restrict__ aoT) {
  int bh = blockIdx.x & 15, qt = blockIdx.x >> 4;
  int b = bh >> 2, head = bh & 3;
  int t = threadIdx.x;
  int wave = t >> 6, lane = t & 63, l15 = lane & 15, quad = lane >> 4;
  int l7 = l15 & 7;
  int qsub = wave >> 1, khalf = wave & 1;

  const unsigned short* Qb = Qt + (size_t)bh * N_ * HD_;
  const unsigned short* Kb = Kt + (size_t)bh * N_ * HD_;
  const unsigned short* Vb = Vv + (size_t)bh * HD_ * N_;
  int q_base = qt * 128 + qsub * 64;

  __shared__ __align__(16) unsigned char smem[65536];
  unsigned short* Ks = (unsigned short*)smem;
  unsigned short* Vs = (unsigned short*)(smem + 32768);
  float* Obuf = (float*)smem;                 // epilogue reuse: qsub*4352 + c*68 + q
  float* lbuf = (float*)(smem + 34816);       // qsub*64 + q

  const short8 vones = {(short)0x3F80, (short)0x3F80, (short)0x3F80, (short)0x3F80,
                        (short)0x3F80, (short)0x3F80, (short)0x3F80, (short)0x3F80};
  const f32x4 fzero = (f32x4){0.f, 0.f, 0.f, 0.f};

  short8 qf[4][2];
#pragma unroll
  for (int r = 0; r < 4; r++)
#pragma unroll
    for (int h = 0; h < 2; h++)
      qf[r][h] = *reinterpret_cast<const short8*>(
          Qb + (size_t)(q_base + r * 16 + l15) * HD_ + h * 32 + quad * 8);

  f32x4 oa[4][4], la[4];
#pragma unroll
  for (int r = 0; r < 4; r++) {
    la[r] = (f32x4){0.f, 0.f, 0.f, 0.f};
#pragma unroll
    for (int ct = 0; ct < 4; ct++) oa[r][ct] = (f32x4){0.f, 0.f, 0.f, 0.f};
  }

  int i8 = lane >> 3, e = lane & 7;
  int perm = (e ^ i8) * 8;   // XOR swizzle of 8-element groups
  int kvoff = (khalf * 2) * 4096;
  auto stage = [&](int kt2, int buf) {
    int m0 = khalf * 2048 + kt2 * 64;
    unsigned short* Kd = Ks + kvoff + buf * 4096;
    unsigned short* Vd = Vs + kvoff + buf * 4096;
#pragma unroll
    for (int cc = 0; cc < 4; cc++) {
      int c = qsub * 4 + cc;
      dma16(Kb + (size_t)(m0 + c * 8 + i8) * HD_ + perm, Kd + c * 512);
      dma16(Vb + (size_t)(c * 8 + i8) * N_ + m0 + perm, Vd + c * 512);
    }
  };

  stage(0, 0);

#pragma unroll 1
  for (int kt = 0; kt < 32; kt++) {
    int buf = kt & 1;
    if (kt + 1 < 32) {
      stage(kt + 1, buf ^ 1);                          // issue prefetch first
      asm volatile("s_waitcnt vmcnt(8)" ::: "memory"); // wait only tile kt's 8
    } else {
      asm volatile("s_waitcnt vmcnt(0)" ::: "memory");
    }
    __builtin_amdgcn_s_barrier();
    __builtin_amdgcn_s_setprio(1);   // compute phase: favor this wave

    const unsigned short* Kbuf = Ks + kvoff + buf * 4096;
    const unsigned short* Vbuf = Vs + kvoff + buf * 4096;

    short8 kf[4][2], vf[4][2];
#pragma unroll
    for (int tt = 0; tt < 4; tt++)
#pragma unroll
      for (int kh2 = 0; kh2 < 2; kh2++) {
        kf[tt][kh2] = *reinterpret_cast<const short8*>(
            &Kbuf[(tt * 16 + l15) * 64 + (((kh2 * 4 + quad) ^ l7) * 8)]);
        vf[tt][kh2] = *reinterpret_cast<const short8*>(
            &Vbuf[(tt * 16 + l15) * 64 + (((kh2 * 4 + quad) ^ l7) * 8)]);
      }

#pragma unroll
    for (int r = 0; r < 4; r++) {
      f32x4 s[4];
#pragma unroll
      for (int tt = 0; tt < 4; tt++) {
        f32x4 z = __builtin_amdgcn_mfma_f32_16x16x32_bf16(kf[tt][0], qf[r][0], fzero, 0, 0, 0);
        s[tt] = __builtin_amdgcn_mfma_f32_16x16x32_bf16(kf[tt][1], qf[r][1], z, 0, 0, 0);
      }
      // exp2 + pack: lane holds P[key=tt*16+quad*4+i][q=l15] as bf16x2 words.
      unsigned Apk[4], Bpk[4];
#pragma unroll
      for (int tt = 0; tt < 4; tt++) {
        Apk[tt] = pkbf2(__builtin_amdgcn_exp2f(s[tt][0]), __builtin_amdgcn_exp2f(s[tt][1]));
        Bpk[tt] = pkbf2(__builtin_amdgcn_exp2f(s[tt][2]), __builtin_amdgcn_exp2f(s[tt][3]));
      }
      // 4x4 quad transpose (fixed l15): PV B-frag lane (l15,quad) needs
      // P[key=quad*8+j][q=l15] -> permlane32_swap (quad^2) + permlane16_swap
      // (quad^1).
      union { unsigned u[4]; short8 v; } f0, f1;
      {
        auto ua = __builtin_amdgcn_permlane32_swap(Apk[0], Apk[1], false, false);
        auto pa = __builtin_amdgcn_permlane16_swap(ua[0], ua[1], false, false);
        auto ub = __builtin_amdgcn_permlane32_swap(Bpk[0], Bpk[1], false, false);
        auto pb = __builtin_amdgcn_permlane16_swap(ub[0], ub[1], false, false);
        f0.u[0] = pa[0]; f0.u[1] = pb[0]; f0.u[2] = pa[1]; f0.u[3] = pb[1];
        auto uc = __builtin_amdgcn_permlane32_swap(Apk[2], Apk[3], false, false);
        auto pc = __builtin_amdgcn_permlane16_swap(uc[0], uc[1], false, false);
        auto ud = __builtin_amdgcn_permlane32_swap(Bpk[2], Bpk[3], false, false);
        auto pd = __builtin_amdgcn_permlane16_swap(ud[0], ud[1], false, false);
        f1.u[0] = pc[0]; f1.u[1] = pd[0]; f1.u[2] = pc[1]; f1.u[3] = pd[1];
      }
      short8 pf0 = f0.v, pf1 = f1.v;
#pragma unroll
      for (int ct = 0; ct < 4; ct++) {
        oa[r][ct] = __builtin_amdgcn_mfma_f32_16x16x32_bf16(vf[ct][0], pf0, oa[r][ct], 0, 0, 0);
        oa[r][ct] = __builtin_amdgcn_mfma_f32_16x16x32_bf16(vf[ct][1], pf1, oa[r][ct], 0, 0, 0);
      }
      la[r] = __builtin_amdgcn_mfma_f32_16x16x32_bf16(vones, pf0, la[r], 0, 0, 0);
      la[r] = __builtin_amdgcn_mfma_f32_16x16x32_bf16(vones, pf1, la[r], 0, 0, 0);
    }
    __builtin_amdgcn_s_setprio(0);   // staging phase next
  }

  // ---- merge the two key-halves (exact: plain add, no max-sub) ----
  __builtin_amdgcn_s_barrier();
  if (khalf == 1) {
#pragma unroll
    for (int r = 0; r < 4; r++) {
#pragma unroll
      for (int ct = 0; ct < 4; ct++)
#pragma unroll
        for (int i = 0; i < 4; i++)
          Obuf[qsub * 4352 + (ct * 16 + quad * 4 + i) * 68 + r * 16 + l15] = oa[r][ct][i];
      if (quad == 0) lbuf[qsub * 64 + r * 16 + l15] = la[r][0];
    }
  }
  __builtin_amdgcn_s_barrier();
  if (khalf == 0) {
#pragma unroll
    for (int r = 0; r < 4; r++) {
      float inv = 1.0f / (la[r][0] + lbuf[qsub * 64 + r * 16 + l15]);
      int n = q_base + r * 16 + l15;
#pragma unroll
      for (int ct = 0; ct < 4; ct++) {
        const float* ob = &Obuf[qsub * 4352 + (ct * 16 + quad * 4) * 68 + r * 16 + l15];
        union { unsigned u2[2]; us4 v; } w;
        w.u2[0] = pkbf2((oa[r][ct][0] + ob[0]) * inv, (oa[r][ct][1] + ob[68]) * inv);
        w.u2[1] = pkbf2((oa[r][ct][2] + ob[136]) * inv, (oa[r][ct][3] + ob[204]) * inv);
        *reinterpret_cast<us4*>(
            aoT + ((size_t)(b * N_ + n)) * C_ + head * HD_ + ct * 16 + quad * 4) = w.v;
      }
    }
  }
}

// ---------------------------------------------------------------------------
// Kernel 5: proj GEMM + bias + residual, 128-n tiles, 1D XCD-aware grid
// (512 blocks): idx = ot*128 + nt*4 + b.
// ---------------------------------------------------------------------------
__global__ __launch_bounds__(256) void proj_gemm(
    const unsigned short* __restrict__ aoT, const unsigned short* __restrict__ wp,
    const float* __restrict__ pb, const float* __restrict__ x,
    float* __restrict__ out) {
  int ot = blockIdx.x >> 7;
  int nt = (blockIdx.x & 127) >> 2;
  int b  = blockIdx.x & 3;
  int t = threadIdx.x;
  int wave = t >> 6, lane = t & 63, l15 = lane & 15, quad = lane >> 4, l7 = l15 & 7;
  int o_base = ot * 64 + wave * 16;

  __shared__ __align__(16) unsigned short sh[128 * C_];
  {
    int row0 = wave * 2 + (lane >> 5);
    int col8 = lane & 31;
    int src8 = (col8 & 24) | ((col8 & 7) ^ (row0 & 7));
    const unsigned short* gsrc = aoT + ((size_t)(b * N_ + nt * 128 + row0)) * C_ + src8 * 8;
#pragma unroll
    for (int it = 0; it < 16; it++)
      dma16(gsrc + (size_t)it * 8 * C_, sh + (it * 8 + wave * 2) * C_);
  }

  f32x4 acc[8];
#pragma unroll
  for (int tt = 0; tt < 8; tt++) acc[tt] = (f32x4){0.f, 0.f, 0.f, 0.f};

  const short8* arow = reinterpret_cast<const short8*>(wp + (size_t)(o_base + l15) * C_);

  asm volatile("s_waitcnt vmcnt(0)" ::: "memory");
  __syncthreads();

#pragma unroll
  for (int kk = 0; kk < 8; kk++) {
    short8 a = arow[kk * 4 + quad];
    int g = kk * 4 + quad;
    int col8 = (g & 24) | ((g & 7) ^ l7);
#pragma unroll
    for (int tt = 0; tt < 8; tt++) {
      short8 bf = *reinterpret_cast<const short8*>(&sh[(tt * 16 + l15) * C_ + col8 * 8]);
      acc[tt] = __builtin_amdgcn_mfma_f32_16x16x32_bf16(a, bf, acc[tt], 0, 0, 0);
    }
  }
#pragma unroll
  for (int tt = 0; tt < 8; tt++) {
    int n = nt * 128 + tt * 16 + l15;
#pragma unroll
    for (int i = 0; i < 4; i++) {
      int o = o_base + quad * 4 + i;
      size_t idx = ((size_t)(b * C_ + o)) * N_ + n;
      out[idx] = acc[tt][i] + pb[o] + x[idx];
    }
  }
}

// ---------------------------------------------------------------------------
extern "C" void kernel_launch(void* const* d_in, const int* in_sizes, int n_in,
                              void* d_out, int out_size, void* d_ws, size_t ws_size,
                              hipStream_t stream) {
  const float* x      = (const float*)d_in[0];
  const float* norm_w = (const float*)d_in[1];
  const float* norm_b = (const float*)d_in[2];
  const float* qkv_w  = (const float*)d_in[3];
  const float* qkv_b  = (const float*)d_in[4];
  const float* proj_w = (const float*)d_in[5];
  const float* proj_b = (const float*)d_in[6];
  float* out = (float*)d_out;

  char* ws = (char*)d_ws;
  size_t off = 0;
  auto alloc = [&](size_t bytes) { size_t o = off; off = (off + bytes + 255) & ~(size_t)255; return o; };
  size_t off_partial = alloc(512 * 2 * sizeof(float));
  size_t off_stats   = alloc(32 * 2 * sizeof(float));   // unused (layout stability)
  size_t off_wq      = alloc((size_t)768 * 256 * 2);
  size_t off_wp      = alloc((size_t)256 * 256 * 2);
  size_t off_hT      = alloc((size_t)B_ * N_ * C_ * 2);
  size_t off_Qt      = alloc((size_t)B_ * NH_ * N_ * HD_ * 2);
  size_t off_Kt      = alloc((size_t)B_ * NH_ * N_ * HD_ * 2);
  size_t off_V       = alloc((size_t)B_ * NH_ * HD_ * N_ * 2);
  size_t off_aoT     = alloc((size_t)B_ * N_ * C_ * 2);
  (void)off_stats;

  float* partial = (float*)(ws + off_partial);
  unsigned short* wq  = (unsigned short*)(ws + off_wq);
  unsigned short* wp  = (unsigned short*)(ws + off_wp);
  unsigned short* hT  = (unsigned short*)(ws + off_hT);
  unsigned short* Qt  = (unsigned short*)(ws + off_Qt);
  unsigned short* Kt  = (unsigned short*)(ws + off_Kt);
  unsigned short* V   = (unsigned short*)(ws + off_V);
  unsigned short* aoT = (unsigned short*)(ws + off_aoT);

  gn_partial_cvt<<<1280, 256, 0, stream>>>(x, partial, qkv_w, proj_w, wq, wp);
  gn_apply<<<dim3(64, 8, 4), 256, 0, stream>>>(x, norm_w, norm_b, partial, hT);
  qkv_gemm<<<768, 256, 0, stream>>>(hT, wq, qkv_b, Qt, Kt, V);
  flash_attn<<<512, 256, 0, stream>>>(Qt, Kt, V, aoT);
  proj_gemm<<<512, 256, 0, stream>>>(aoT, wp, proj_b, x, out);
}